// Round 7
// baseline (428.506 us; speedup 1.0000x reference)
//
#include <hip/hip_runtime.h>
#include <hip/hip_bf16.h>

#define N_NODES     65536
#define N_EDGES     524288
#define N_GRAPHS    512
#define G_NODES_N   10000
#define NUM_DIS     2000
#define IN_DIM      128
#define HID         256
#define D_FEAT      512
#define POOL_SPLIT  8

typedef _Float16 half8 __attribute__((ext_vector_type(8)));
typedef _Float16 half4v __attribute__((ext_vector_type(4)));
typedef float    f32x4 __attribute__((ext_vector_type(4)));

typedef __attribute__((address_space(1))) const void as1_void;
typedef __attribute__((address_space(3))) void       as3_void;

// ---------------------------------------------------------------------------
// 1. Tiled weight transpose+convert: 64x64 LDS tiles, coalesced both ways.
//    blocks 0..63: W1,W2,Ws,Wn (256x256); 64..95: Wd,Wc (512x128)
// ---------------------------------------------------------------------------
__global__ __launch_bounds__(256) void wcvt_all_kernel(
    const float* __restrict__ W1, const float* __restrict__ W2,
    const float* __restrict__ Ws, const float* __restrict__ Wn,
    const float* __restrict__ Wd, const float* __restrict__ Wc,
    _Float16* __restrict__ W1T, _Float16* __restrict__ W2T,
    _Float16* __restrict__ WsT, _Float16* __restrict__ WnT,
    _Float16* __restrict__ WdT, _Float16* __restrict__ WcT)
{
    __shared__ float tile[64][65];
    const int b = blockIdx.x;
    const int mat = b >> 4, t = b & 15;
    const float* W; _Float16* T; int K, N, k0, n0;
    if (mat < 4) {
        K = HID; N = HID; k0 = (t >> 2) * 64; n0 = (t & 3) * 64;
        W = (mat == 0) ? W1 : (mat == 1) ? W2 : (mat == 2) ? Ws : Wn;
        T = (mat == 0) ? W1T : (mat == 1) ? W2T : (mat == 2) ? WsT : WnT;
    } else {
        K = D_FEAT; N = IN_DIM; k0 = (t >> 1) * 64; n0 = (t & 1) * 64;
        W = (mat == 4) ? Wd : Wc;
        T = (mat == 4) ? WdT : WcT;
    }
    const int tx = threadIdx.x & 63, ty = threadIdx.x >> 6;
    #pragma unroll
    for (int r = 0; r < 64; r += 4)
        tile[r + ty][tx] = W[(size_t)(k0 + r + ty) * N + n0 + tx];
    __syncthreads();
    #pragma unroll
    for (int c = 0; c < 64; c += 4)
        T[(size_t)(n0 + c + ty) * K + k0 + tx] = (_Float16)tile[tx][c + ty];
}

// ---------------------------------------------------------------------------
// 2. Projection GEMM (MFMA), both segments in one dispatch.
// ---------------------------------------------------------------------------
__global__ __launch_bounds__(256) void proj_mfma_kernel(
    const float* __restrict__ dtab, const float* __restrict__ ctab,
    const _Float16* __restrict__ WdT, const _Float16* __restrict__ WcT,
    _Float16* __restrict__ proj)
{
    __shared__ _Float16 Alds[128 * 40];
    __shared__ _Float16 Blds[128 * 40];
    const int blk = blockIdx.x;
    const float* tab; const _Float16* WT; int base, M, bm;
    if (blk < 16) { tab = dtab; WT = WdT; base = 0;           M = NUM_DIS + 1;             bm = blk * 128; }
    else          { tab = ctab; WT = WcT; base = NUM_DIS + 1; M = G_NODES_N - NUM_DIS - 1; bm = (blk - 16) * 128; }
    const int tid  = threadIdx.x;
    const int wave = tid >> 6, lane = tid & 63;
    const int q    = lane >> 4, l16 = lane & 15;
    const int mbase = (wave & 1) * 64, nbase = (wave >> 1) * 64;
    const int r = tid >> 1, s = tid & 1;

    f32x4 acc[4][4] = {};

    for (int kc = 0; kc < 16; ++kc) {
        const int k0 = kc * 32;
        const int arow = min(bm + r, M - 1);
        const float* gA = tab + (size_t)(base + arow) * D_FEAT + k0 + s * 16;
        const _Float16* gB = WT + (size_t)r * D_FEAT + k0 + s * 16;
        const float4 f0 = ((const float4*)gA)[0];
        const float4 f1 = ((const float4*)gA)[1];
        const float4 f2 = ((const float4*)gA)[2];
        const float4 f3 = ((const float4*)gA)[3];
        const half8 hb0 = *(const half8*)gB;
        const half8 hb1 = *(const half8*)(gB + 8);
        half8 h0, h1;
        h0[0]=(_Float16)f0.x; h0[1]=(_Float16)f0.y; h0[2]=(_Float16)f0.z; h0[3]=(_Float16)f0.w;
        h0[4]=(_Float16)f1.x; h0[5]=(_Float16)f1.y; h0[6]=(_Float16)f1.z; h0[7]=(_Float16)f1.w;
        h1[0]=(_Float16)f2.x; h1[1]=(_Float16)f2.y; h1[2]=(_Float16)f2.z; h1[3]=(_Float16)f2.w;
        h1[4]=(_Float16)f3.x; h1[5]=(_Float16)f3.y; h1[6]=(_Float16)f3.z; h1[7]=(_Float16)f3.w;
        __syncthreads();
        *(half8*)&Alds[r * 40 + s * 16]     = h0;
        *(half8*)&Alds[r * 40 + s * 16 + 8] = h1;
        *(half8*)&Blds[r * 40 + s * 16]     = hb0;
        *(half8*)&Blds[r * 40 + s * 16 + 8] = hb1;
        __syncthreads();
        half8 a[4], b[4];
        #pragma unroll
        for (int i = 0; i < 4; ++i)
            a[i] = *(const half8*)&Alds[(mbase + i * 16 + l16) * 40 + q * 8];
        #pragma unroll
        for (int j = 0; j < 4; ++j)
            b[j] = *(const half8*)&Blds[(nbase + j * 16 + l16) * 40 + q * 8];
        #pragma unroll
        for (int i = 0; i < 4; ++i)
            #pragma unroll
            for (int j = 0; j < 4; ++j)
                acc[i][j] = __builtin_amdgcn_mfma_f32_16x16x32_f16(a[i], b[j], acc[i][j], 0, 0, 0);
    }

    #pragma unroll
    for (int j = 0; j < 4; ++j) {
        const int colg = nbase + j * 16 + l16;   // 0..127
        #pragma unroll
        for (int i = 0; i < 4; ++i) {
            #pragma unroll
            for (int rr = 0; rr < 4; ++rr) {
                const int row = bm + mbase + i * 16 + q * 4 + rr;
                if (row < M)
                    proj[(size_t)(base + row) * IN_DIM + colg] = (_Float16)acc[i][j][rr];
            }
        }
    }
}

// ---------------------------------------------------------------------------
// 3. x = concat(z_table[z], proj[node_id])  -> f16  [N_NODES, 256]
// ---------------------------------------------------------------------------
__global__ __launch_bounds__(256) void build_x_kernel(
    const int* __restrict__ z, const int* __restrict__ node_id,
    const float* __restrict__ z_table, const _Float16* __restrict__ proj,
    _Float16* __restrict__ X)
{
    const int t = blockIdx.x * 256 + threadIdx.x;   // < N_NODES*64
    const int node = t >> 6;
    const int q    = t & 63;
    half4v h;
    if (q < 32) {
        const float4 v = ((const float4*)(z_table + (size_t)z[node] * IN_DIM))[q];
        h[0] = (_Float16)v.x; h[1] = (_Float16)v.y;
        h[2] = (_Float16)v.z; h[3] = (_Float16)v.w;
    } else {
        h = *(const half4v*)(proj + (size_t)node_id[node] * IN_DIM + (q - 32) * 4);
    }
    *(half4v*)(X + (size_t)node * HID + q * 4) = h;
}

// ---------------------------------------------------------------------------
// 4. CSR build: hist -> 3-phase hierarchical scan -> scatter
// ---------------------------------------------------------------------------
__global__ __launch_bounds__(256) void hist_kernel(
    const int* __restrict__ dst, int* __restrict__ cnt)
{
    const int e = blockIdx.x * 256 + threadIdx.x;
    if (e < N_EDGES) atomicAdd(&cnt[dst[e]], 1);
}

__global__ __launch_bounds__(256) void seg_sum_kernel(
    const int* __restrict__ cnt, int* __restrict__ seg)
{
    __shared__ int red[256];
    const int t = threadIdx.x;
    const int4 c = *(const int4*)(cnt + blockIdx.x * 1024 + t * 4);
    red[t] = c.x + c.y + c.z + c.w;
    __syncthreads();
    for (int s = 128; s > 0; s >>= 1) {
        if (t < s) red[t] += red[t + s];
        __syncthreads();
    }
    if (t == 0) seg[blockIdx.x] = red[0];
}

__global__ __launch_bounds__(64) void seg_scan_kernel(
    const int* __restrict__ seg, int* __restrict__ segoff,
    int* __restrict__ total_out)
{
    __shared__ int a[64], b[64];
    const int t = threadIdx.x;
    const int v = seg[t];
    a[t] = v;
    __syncthreads();
    int* in = a; int* out = b;
    for (int off = 1; off < 64; off <<= 1) {
        out[t] = in[t] + ((t >= off) ? in[t - off] : 0);
        __syncthreads();
        int* tmp = in; in = out; out = tmp;
    }
    segoff[t] = in[t] - v;
    if (t == 63) total_out[0] = in[63];
}

__global__ __launch_bounds__(256) void local_scan_kernel(
    const int* __restrict__ cnt, const int* __restrict__ segoff,
    int* __restrict__ row_ptr, int* __restrict__ fill)
{
    __shared__ int a[256], b[256];
    const int t = threadIdx.x;
    const int base = blockIdx.x * 1024 + t * 4;
    const int4 c = *(const int4*)(cnt + base);
    const int s = c.x + c.y + c.z + c.w;
    a[t] = s;
    __syncthreads();
    int* in = a; int* out = b;
    for (int off = 1; off < 256; off <<= 1) {
        out[t] = in[t] + ((t >= off) ? in[t - off] : 0);
        __syncthreads();
        int* tmp = in; in = out; out = tmp;
    }
    const int run = in[t] - s + segoff[blockIdx.x];
    int4 r;
    r.x = run; r.y = run + c.x; r.z = r.y + c.y; r.w = r.z + c.z;
    *(int4*)(row_ptr + base) = r;
    *(int4*)(fill + base) = r;
}

__global__ __launch_bounds__(256) void scatter_kernel(
    const int* __restrict__ src, const int* __restrict__ dst,
    int* __restrict__ fill, int* __restrict__ col)
{
    const int e = blockIdx.x * 256 + threadIdx.x;
    if (e < N_EDGES) {
        const int pos = atomicAdd(&fill[dst[e]], 1);
        col[pos] = src[e];
    }
}

// ---------------------------------------------------------------------------
// 5. CSR gather-aggregation: 32 lanes/row (16B loads).
// ---------------------------------------------------------------------------
__global__ __launch_bounds__(256) void csr_agg_kernel(
    const int* __restrict__ row_ptr, const int* __restrict__ col,
    const _Float16* __restrict__ F, const _Float16* __restrict__ Self,
    _Float16* __restrict__ OUT, const int mean_mode)
{
    const int t = blockIdx.x * 256 + threadIdx.x;   // < N_NODES*32
    const int d = t >> 5;
    const int q = t & 31;
    const int beg = row_ptr[d];
    const int end = row_ptr[d + 1];
    float acc[8] = {0.f,0.f,0.f,0.f,0.f,0.f,0.f,0.f};
    if (Self) {
        const half8 sv = *(const half8*)(Self + (size_t)d * HID + q * 8);
        #pragma unroll
        for (int i = 0; i < 8; ++i) acc[i] = (float)sv[i];
    }
    int e = beg;
    for (; e + 4 <= end; e += 4) {
        const int s0 = col[e],     s1 = col[e + 1];
        const int s2 = col[e + 2], s3 = col[e + 3];
        const half8 v0 = *(const half8*)(F + (size_t)s0 * HID + q * 8);
        const half8 v1 = *(const half8*)(F + (size_t)s1 * HID + q * 8);
        const half8 v2 = *(const half8*)(F + (size_t)s2 * HID + q * 8);
        const half8 v3 = *(const half8*)(F + (size_t)s3 * HID + q * 8);
        #pragma unroll
        for (int i = 0; i < 8; ++i)
            acc[i] += ((float)v0[i] + (float)v1[i]) + ((float)v2[i] + (float)v3[i]);
    }
    for (; e < end; ++e) {
        const half8 v0 = *(const half8*)(F + (size_t)col[e] * HID + q * 8);
        #pragma unroll
        for (int i = 0; i < 8; ++i) acc[i] += (float)v0[i];
    }
    if (mean_mode) {
        const float rs = 1.0f / fmaxf((float)(end - beg), 1.0f);
        #pragma unroll
        for (int i = 0; i < 8; ++i) acc[i] *= rs;
    }
    half8 o;
    #pragma unroll
    for (int i = 0; i < 8; ++i) o[i] = (_Float16)acc[i];
    *(half8*)(OUT + (size_t)d * HID + q * 8) = o;
}

// ---------------------------------------------------------------------------
// 6. MFMA f16 GEMM with global_load_lds (width 16) staging.
//    C = act( [A1|A2] @ [B1;B2] + bias ) -> f16
//    BM=BN=128, BK=32, 4 waves. LDS layout [row][32] halfs, UNPADDED and
//    lane-contiguous in segment order (global_load_lds requirement).
// ---------------------------------------------------------------------------
__global__ __launch_bounds__(256) void mfma_gemm_kernel(
    const _Float16* __restrict__ A1, const _Float16* __restrict__ A2,
    const _Float16* __restrict__ B1T, const _Float16* __restrict__ B2T,
    const float* __restrict__ bias, _Float16* __restrict__ Ch, const int relu)
{
    __shared__ _Float16 Alds[128 * 32];
    __shared__ _Float16 Blds[128 * 32];
    const int bm   = blockIdx.x * 128;
    const int bn   = blockIdx.y * 128;
    const int tid  = threadIdx.x;
    const int wave = tid >> 6, lane = tid & 63;
    const int q    = lane >> 4, l16 = lane & 15;
    const int mbase = (wave & 1) * 64, nbase = (wave >> 1) * 64;

    f32x4 acc[4][4] = {};
    const int nchunks = A2 ? 16 : 8;

    for (int kc = 0; kc < nchunks; ++kc) {
        const int k0 = (kc & 7) * 32;
        const _Float16* Abase = (kc < 8) ? A1 : A2;
        const _Float16* Bbase = (kc < 8) ? B1T : B2T;
        __syncthreads();   // previous iteration's readers done
        #pragma unroll
        for (int t = 0; t < 2; ++t) {
            const int i   = wave * 128 + t * 64 + lane;   // segment 0..511
            const int row = i >> 2, s = i & 3;            // 16B seg s of row
            const _Float16* gA = Abase + (size_t)(bm + row) * HID + k0 + s * 8;
            const _Float16* gB = Bbase + (size_t)(bn + row) * HID + k0 + s * 8;
            __builtin_amdgcn_global_load_lds(
                (as1_void*)gA, (as3_void*)&Alds[(wave * 128 + t * 64) * 8], 16, 0, 0);
            __builtin_amdgcn_global_load_lds(
                (as1_void*)gB, (as3_void*)&Blds[(wave * 128 + t * 64) * 8], 16, 0, 0);
        }
        __syncthreads();   // DMA drained (compiler emits vmcnt(0) before barrier)
        half8 a[4], b[4];
        #pragma unroll
        for (int i = 0; i < 4; ++i)
            a[i] = *(const half8*)&Alds[(mbase + i * 16 + l16) * 32 + q * 8];
        #pragma unroll
        for (int j = 0; j < 4; ++j)
            b[j] = *(const half8*)&Blds[(nbase + j * 16 + l16) * 32 + q * 8];
        #pragma unroll
        for (int i = 0; i < 4; ++i)
            #pragma unroll
            for (int j = 0; j < 4; ++j)
                acc[i][j] = __builtin_amdgcn_mfma_f32_16x16x32_f16(a[i], b[j], acc[i][j], 0, 0, 0);
    }

    #pragma unroll
    for (int j = 0; j < 4; ++j) {
        const int colg = bn + nbase + j * 16 + l16;
        const float bv = bias ? bias[colg] : 0.0f;
        #pragma unroll
        for (int i = 0; i < 4; ++i) {
            #pragma unroll
            for (int rr = 0; rr < 4; ++rr) {
                const int rowg = bm + mbase + i * 16 + q * 4 + rr;
                float v = acc[i][j][rr] + bv;
                if (relu) v = fmaxf(v, 0.0f);
                Ch[(size_t)rowg * HID + colg] = (_Float16)v;
            }
        }
    }
}

// ---------------------------------------------------------------------------
// 7a. Parallel partial max-pool: POOL_SPLIT blocks per graph, no atomics.
// ---------------------------------------------------------------------------
__global__ __launch_bounds__(256) void pool_part_kernel(
    const _Float16* __restrict__ H2, const int* __restrict__ gid,
    float* __restrict__ Gpart)
{
    const int g = blockIdx.y;     // 0..511
    const int sp = blockIdx.x;    // 0..POOL_SPLIT-1
    const int j = threadIdx.x;    // 0..255
    int lo = 0, hi = N_NODES;
    while (lo < hi) { const int mid = (lo + hi) >> 1; if (gid[mid] < g) lo = mid + 1; else hi = mid; }
    const int start = lo;
    hi = N_NODES;
    while (lo < hi) { const int mid = (lo + hi) >> 1; if (gid[mid] < g + 1) lo = mid + 1; else hi = mid; }
    const int end = lo;
    float m = -INFINITY;
    for (int i = start + sp; i < end; i += POOL_SPLIT)
        m = fmaxf(m, (float)H2[(size_t)i * HID + j]);
    Gpart[((size_t)g * POOL_SPLIT + sp) * HID + j] = m;
}

// ---------------------------------------------------------------------------
// 7b. Head: reduce partials + MLP.  out[g]=relu(max@lin1+b1)@lin2+b2
// ---------------------------------------------------------------------------
__global__ __launch_bounds__(256) void head_kernel(
    const float* __restrict__ Gpart,
    const float* __restrict__ W1, const float* __restrict__ b1,
    const float* __restrict__ W2, const float* __restrict__ b2,
    float* __restrict__ out)
{
    const int g = blockIdx.x;
    const int j = threadIdx.x;
    __shared__ float row[HID];
    __shared__ float red[HID];
    float m = -INFINITY;
    #pragma unroll
    for (int sp = 0; sp < POOL_SPLIT; ++sp)
        m = fmaxf(m, Gpart[((size_t)g * POOL_SPLIT + sp) * HID + j]);
    row[j] = (m == -INFINITY) ? 0.0f : m;
    __syncthreads();
    float acc = b1[j];
    #pragma unroll 8
    for (int k = 0; k < HID; ++k)
        acc = fmaf(row[k], W1[k * HID + j], acc);
    acc = fmaxf(acc, 0.f);
    red[j] = acc * W2[j];
    __syncthreads();
    for (int s = 128; s > 0; s >>= 1) {
        if (j < s) red[j] += red[j + s];
        __syncthreads();
    }
    if (j == 0) out[g] = red[0] + b2[0];
}

// ---------------------------------------------------------------------------
extern "C" void kernel_launch(void* const* d_in, const int* in_sizes, int n_in,
                              void* d_out, int out_size, void* d_ws, size_t ws_size,
                              hipStream_t stream)
{
    const int*   z         = (const int*)d_in[0];
    const int*   node_id   = (const int*)d_in[1];
    const int*   src       = (const int*)d_in[2];
    const int*   dst       = (const int*)d_in[3];
    const int*   graph_ids = (const int*)d_in[4];
    const float* z_table   = (const float*)d_in[5];
    const float* d_feat    = (const float*)d_in[6];
    const float* c_feat    = (const float*)d_in[7];
    const float* Wd        = (const float*)d_in[8];
    const float* Wc        = (const float*)d_in[9];
    const float* gin_W1    = (const float*)d_in[10];
    const float* gin_b1    = (const float*)d_in[11];
    const float* gin_W2    = (const float*)d_in[12];
    const float* gin_b2    = (const float*)d_in[13];
    const float* sage_Wself  = (const float*)d_in[14];
    const float* sage_Wneigh = (const float*)d_in[15];
    const float* sage_b    = (const float*)d_in[16];
    const float* lin1_W    = (const float*)d_in[17];
    const float* lin1_b    = (const float*)d_in[18];
    const float* lin2_W    = (const float*)d_in[19];
    const float* lin2_b    = (const float*)d_in[20];
    float* out = (float*)d_out;

    // ---- workspace carve-up ----
    const size_t NH = (size_t)N_NODES * HID;        // 16,777,216 elements
    char* wsb = (char*)d_ws;
    _Float16* bufA = (_Float16*)wsb;                     wsb += NH * 2;  // Xh -> Hh
    _Float16* AGGh = (_Float16*)wsb;                     wsb += NH * 2;  // both aggs
    _Float16* H1h  = (_Float16*)wsb;                     wsb += NH * 2;  // H1 -> H2
    _Float16* projh= (_Float16*)wsb;                     wsb += (size_t)G_NODES_N * IN_DIM * 2;
    _Float16* W1T  = (_Float16*)wsb;                     wsb += HID * HID * 2;
    _Float16* W2T  = (_Float16*)wsb;                     wsb += HID * HID * 2;
    _Float16* WsT  = (_Float16*)wsb;                     wsb += HID * HID * 2;
    _Float16* WnT  = (_Float16*)wsb;                     wsb += HID * HID * 2;
    _Float16* WdT  = (_Float16*)wsb;                     wsb += D_FEAT * IN_DIM * 2;
    _Float16* WcT  = (_Float16*)wsb;                     wsb += D_FEAT * IN_DIM * 2;
    float* Gpart   = (float*)wsb;                        wsb += (size_t)N_GRAPHS * POOL_SPLIT * HID * 4;
    int* row_ptr   = (int*)wsb;                          wsb += (N_NODES + 4) * 4;
    int* cnt       = (int*)wsb;                          wsb += N_NODES * 4;
    int* fill      = (int*)wsb;                          wsb += N_NODES * 4;
    int* col       = (int*)wsb;                          wsb += N_EDGES * 4;
    int* seg       = (int*)wsb;                          wsb += 64 * 4;
    int* segoff    = (int*)wsb;                          wsb += 64 * 4;

    _Float16* Xh  = bufA;
    _Float16* Hh  = bufA;   // reuse after X dead
    _Float16* H2h = H1h;    // reuse after H1 dead

    // ---- CSR build ----
    hipMemsetAsync(cnt, 0, N_NODES * sizeof(int), stream);
    hist_kernel<<<N_EDGES / 256, 256, 0, stream>>>(dst, cnt);
    seg_sum_kernel<<<64, 256, 0, stream>>>(cnt, seg);
    seg_scan_kernel<<<1, 64, 0, stream>>>(seg, segoff, &row_ptr[N_NODES]);
    local_scan_kernel<<<64, 256, 0, stream>>>(cnt, segoff, row_ptr, fill);
    scatter_kernel<<<N_EDGES / 256, 256, 0, stream>>>(src, dst, fill, col);

    // ---- weights -> f16 transposed (tiled, one dispatch) ----
    wcvt_all_kernel<<<96, 256, 0, stream>>>(gin_W1, gin_W2, sage_Wself, sage_Wneigh,
                                            Wd, Wc, W1T, W2T, WsT, WnT, WdT, WcT);

    // ---- projection table via MFMA ----
    proj_mfma_kernel<<<16 + 63, 256, 0, stream>>>(d_feat, c_feat, WdT, WcT, projh);

    // ---- build x ----
    build_x_kernel<<<(N_NODES * 64) / 256, 256, 0, stream>>>(z, node_id, z_table, projh, Xh);

    // ---- GIN aggregation: AGG = X + sum_neigh(X) ----
    csr_agg_kernel<<<(N_NODES * 32) / 256, 256, 0, stream>>>(row_ptr, col, Xh, Xh, AGGh, 0);

    // ---- GIN MLP: H1 = relu(AGG@W1+b1); H = H1@W2+b2 ----
    dim3 ggrid(N_NODES / 128, HID / 128);
    mfma_gemm_kernel<<<ggrid, 256, 0, stream>>>(AGGh, nullptr, W1T, nullptr, gin_b1, H1h, 1);
    mfma_gemm_kernel<<<ggrid, 256, 0, stream>>>(H1h, nullptr, W2T, nullptr, gin_b2, Hh, 0);

    // ---- SAGE mean aggregation: AGG = mean_neigh(H) ----
    csr_agg_kernel<<<(N_NODES * 32) / 256, 256, 0, stream>>>(row_ptr, col, Hh, nullptr, AGGh, 1);

    // ---- SAGE fused: H2 = H@Wself + AGG@Wneigh + b  (K=512) ----
    mfma_gemm_kernel<<<ggrid, 256, 0, stream>>>(Hh, AGGh, WsT, WnT, sage_b, H2h, 0);

    // ---- parallel max pool + head ----
    dim3 pgrid(POOL_SPLIT, N_GRAPHS);
    pool_part_kernel<<<pgrid, 256, 0, stream>>>(H2h, graph_ids, Gpart);
    head_kernel<<<N_GRAPHS, 256, 0, stream>>>(Gpart, lin1_W, lin1_b, lin2_W, lin2_b, out);
}